// Round 5
// baseline (328.725 us; speedup 1.0000x reference)
//
#include <hip/hip_runtime.h>

typedef float f32x4 __attribute__((ext_vector_type(4)));
typedef __bf16 bf16x8 __attribute__((ext_vector_type(8)));
typedef __bf16 bf16x4 __attribute__((ext_vector_type(4)));

#define MFMA16(a, b, c) __builtin_amdgcn_mfma_f32_16x16x32_bf16((a), (b), (c), 0, 0, 0)

// Async global->LDS, 16B per lane. Dest is wave-uniform base + lane*16 (linear).
__device__ __forceinline__ void gl16(const void* g, void* l) {
    __builtin_amdgcn_global_load_lds(
        (const __attribute__((address_space(1))) void*)g,
        (__attribute__((address_space(3))) void*)l, 16, 0, 0);
}

// Raw prefetch container (fp32 operands only): keep fp32 loads unconverted so
// the cvt (and its waitcnt) lands at LDS-write time, a full iteration later.
template<int F> struct Raw;
template<> struct Raw<0> { bf16x8 v; };
template<> struct Raw<1> { f32x4 a, b; };

template<int F>
__device__ __forceinline__ Raw<F> ldraw(const void* p, size_t idx) {
    Raw<F> r;
    if constexpr (F) {
        const float* q = (const float*)p + idx;
        r.a = *(const f32x4*)q;
        r.b = *(const f32x4*)(q + 4);
    } else {
        r.v = *(const bf16x8*)((const __bf16*)p + idx);
    }
    return r;
}
template<int F>
__device__ __forceinline__ bf16x8 toBf(const Raw<F>& r) {
    if constexpr (F) {
        bf16x8 o;
        o[0] = (__bf16)r.a[0]; o[1] = (__bf16)r.a[1]; o[2] = (__bf16)r.a[2]; o[3] = (__bf16)r.a[3];
        o[4] = (__bf16)r.b[0]; o[5] = (__bf16)r.b[1]; o[6] = (__bf16)r.b[2]; o[7] = (__bf16)r.b[3];
        return o;
    } else {
        return r.v;
    }
}

// ---------------------------------------------------------------------------
// cvt: fp32 -> bf16 bulk convert (Wck / Wcv).
// ---------------------------------------------------------------------------
__global__ __launch_bounds__(256) void cvt(
    const float* __restrict__ a0, const float* __restrict__ a1,
    __bf16* __restrict__ o0, __bf16* __restrict__ o1)
{
    const float* a = blockIdx.y ? a1 : a0;
    __bf16* o = blockIdx.y ? o1 : o0;
    size_t i = ((size_t)blockIdx.x * 256 + threadIdx.x) * 4;
    f32x4 v = *(const f32x4*)&a[i];
    bf16x4 r; r[0]=(__bf16)v[0]; r[1]=(__bf16)v[1]; r[2]=(__bf16)v[2]; r[3]=(__bf16)v[3];
    *(bf16x4*)&o[i] = r;
}

// ---------------------------------------------------------------------------
// tq: query fp32 [4096 t][2048 n] -> qT bf16 [2048 n][4096 t].
// ---------------------------------------------------------------------------
__global__ __launch_bounds__(256) void tq(
    const float* __restrict__ q, __bf16* __restrict__ qT)
{
    __shared__ float Ts[64][65];
    const int t0 = blockIdx.x * 64, n0 = blockIdx.y * 64;
    const int tid = threadIdx.x;
    const int r = tid >> 4, c4 = (tid & 15) * 4;
    for (int p = 0; p < 4; p++) {
        f32x4 v = *(const f32x4*)&q[(size_t)(t0 + r + 16 * p) * 2048 + n0 + c4];
        Ts[r + 16 * p][c4 + 0] = v[0];
        Ts[r + 16 * p][c4 + 1] = v[1];
        Ts[r + 16 * p][c4 + 2] = v[2];
        Ts[r + 16 * p][c4 + 3] = v[3];
    }
    __syncthreads();
    for (int p = 0; p < 4; p++) {
        const int nrow = r + 16 * p;
        bf16x4 o;
        o[0] = (__bf16)Ts[c4 + 0][nrow];
        o[1] = (__bf16)Ts[c4 + 1][nrow];
        o[2] = (__bf16)Ts[c4 + 2][nrow];
        o[3] = (__bf16)Ts[c4 + 3][nrow];
        *(bf16x4*)&qT[(size_t)(n0 + nrow) * 4096 + t0 + c4] = o;
    }
}

// ---------------------------------------------------------------------------
// tv: vp bf16 [4096 (4c+b)][512 (64h+d)] -> vpT bf16 [32 bh][64 d][1024 c'],
// with c' sigma-permuted inside each 64-block: sigma(cc)=4*(cc&15)+(cc>>4).
// ---------------------------------------------------------------------------
__global__ __launch_bounds__(256) void tv(
    const __bf16* __restrict__ vp, __bf16* __restrict__ vpT)
{
    __shared__ __bf16 Ts[64][72];   // [cc][d]
    const int c0 = blockIdx.x * 64;
    const int bh = blockIdx.y, b = bh >> 3, h = bh & 7;
    const int tid = threadIdx.x;
    const int cr = tid >> 3, a8 = (tid & 7) * 8;
    for (int p = 0; p < 2; p++) {
        bf16x8 v = *(const bf16x8*)&vp[(size_t)(4 * (c0 + cr + 32 * p) + b) * 512 + h * 64 + a8];
        *(bf16x8*)&Ts[cr + 32 * p][a8] = v;
    }
    __syncthreads();
    for (int p = 0; p < 2; p++) {
        const int d = cr + 32 * p;
        bf16x8 o;
        for (int u = 0; u < 8; u++) {
            const int pos = a8 + u;                       // permuted position
            const int cc = (pos & 3) * 16 + (pos >> 2);   // source key index
            o[u] = Ts[cc][d];
        }
        *(bf16x8*)&vpT[((size_t)bh * 64 + d) * 1024 + c0 + a8] = o;
    }
}

// ---------------------------------------------------------------------------
// NT GEMM: C = (A @ W^T + bias) * scale.  A:[M,K], W:[N,K] rm.
// BK=64, double-buffered LDS, ONE barrier per K-step.
// Round-5: BN reverted to 128 everywhere. R4's BN=64 doubled grid.x and with
// it the A-panel re-fetch (g1/g5: 33.5MB fp32 read 8x instead of 4x) plus
// +33% LDS fragment traffic -> net +25us regression. The 2-blocks/CU config
// with BN=128 is the measured optimum for this latency/BW balance.
// LDS: As 16/32KB + Ws 32KB. Swizzle: slot (r, chunk j) holds logical chunk
// j ^ (r&7); both-sides (pre-swizzled gload source / swizzled ds_write+read).
// ---------------------------------------------------------------------------
template<int BM, int BN, int AF, int WF, int CF, int BIAS>
__global__ __launch_bounds__(256) void gemm_nt(
    const void* __restrict__ A0, const void* __restrict__ A1,
    const void* __restrict__ W0, const void* __restrict__ W1,
    const void* __restrict__ b0, const void* __restrict__ b1,
    void* __restrict__ C0, void* __restrict__ C1,
    int M, int N, int K, float scale)
{
    const void* A = blockIdx.z ? A1 : A0;
    const void* W = blockIdx.z ? W1 : W0;
    const void* bias = blockIdx.z ? b1 : b0;
    void* C = blockIdx.z ? C1 : C0;

    __shared__ __attribute__((aligned(16))) __bf16 As[2][BM][64];
    __shared__ __attribute__((aligned(16))) __bf16 Ws[2][BN][64];

    const int n0 = blockIdx.x * BN;
    const int m0 = blockIdx.y * BM;
    const int tid = threadIdx.x;
    const int lane = tid & 63, wv = tid >> 6;
    const int quad = lane >> 4, l15 = lane & 15;
    constexpr int WR = BM / 2, MI = WR / 16;
    constexpr int WC = BN / 2, NJ = WC / 16;
    const int wrow = (wv >> 1) * WR, wcol = (wv & 1) * WC;

    // gload_lds geometry: one instr = 8 rows x 128B, dest linear from a
    // wave-uniform base. Lane l lands at (row base+l>>3, chunk l&7); to build
    // the swizzled layout it loads global chunk (l&7) ^ (l>>3).
    const int lrow = lane >> 3;
    const int csrc = ((lane & 7) ^ lrow) * 8;   // source chunk, in elements

    // fp32 reg-staging geometry: thread handles (row tid>>3 + 32p, chunk tid&7),
    // written to the swizzled slot so reads are layout-identical to gload path.
    const int srow = tid >> 3;
    const int sj = tid & 7;
    const int swc = (sj ^ (srow & 7)) * 8;      // swizzled dest column

    constexpr int AP = BM / 32;
    constexpr int WP = BN / 32;
    Raw<AF> pa[AP];
    Raw<WF> pw[WP];

    auto stageA = [&](int buf, int kt) {
        if constexpr (AF == 0) {
            for (int p = 0; p < AP; p++)
                gl16((const __bf16*)A + (size_t)(m0 + wv * 8 + p * 32 + lrow) * K + kt + csrc,
                     &As[buf][wv * 8 + p * 32][0]);
        } else {
            (void)kt;
            for (int p = 0; p < AP; p++)
                *(bf16x8*)&As[buf][srow + 32 * p][swc] = toBf<AF>(pa[p]);
        }
    };
    auto stageW = [&](int buf, int kt) {
        if constexpr (WF == 0) {
            for (int p = 0; p < WP; p++)
                gl16((const __bf16*)W + (size_t)(n0 + wv * 8 + p * 32 + lrow) * K + kt + csrc,
                     &Ws[buf][wv * 8 + p * 32][0]);
        } else {
            (void)kt;
            for (int p = 0; p < WP; p++)
                *(bf16x8*)&Ws[buf][srow + 32 * p][swc] = toBf<WF>(pw[p]);
        }
    };
    auto loadA = [&](int kt) {
        if constexpr (AF == 1)
            for (int p = 0; p < AP; p++)
                pa[p] = ldraw<AF>(A, (size_t)(m0 + srow + 32 * p) * K + kt + sj * 8);
    };
    auto loadW = [&](int kt) {
        if constexpr (WF == 1)
            for (int p = 0; p < WP; p++)
                pw[p] = ldraw<WF>(W, (size_t)(n0 + srow + 32 * p) * K + kt + sj * 8);
    };

    f32x4 acc[MI][NJ];
    for (int i = 0; i < MI; i++)
        for (int j = 0; j < NJ; j++)
            acc[i][j] = (f32x4){0.f, 0.f, 0.f, 0.f};

    // prologue: tile 0 -> buf 0; fp32 operands additionally prefetch tile 1
    loadA(0);
    loadW(0);
    stageA(0, 0);
    stageW(0, 0);
    loadA(64);
    loadW(64);
    __syncthreads();

    const int NT = K >> 6;
    for (int t = 0; t < NT; ++t) {
        const int cur = t & 1;
        if (t + 1 < NT) {
            stageA(cur ^ 1, (t + 1) * 64);   // fp32 path: writes pregs (tile t+1)
            stageW(cur ^ 1, (t + 1) * 64);
            if (t + 2 < NT) { loadA((t + 2) * 64); loadW((t + 2) * 64); }
        }
        bf16x8 a0[MI], a1[MI], bv0[NJ], bv1[NJ];
        for (int i = 0; i < MI; i++) {
            const int r = wrow + i * 16 + l15;
            a0[i] = *(const bf16x8*)&As[cur][r][(quad ^ (r & 7)) * 8];
            a1[i] = *(const bf16x8*)&As[cur][r][((4 + quad) ^ (r & 7)) * 8];
        }
        for (int j = 0; j < NJ; j++) {
            const int r = wcol + j * 16 + l15;
            bv0[j] = *(const bf16x8*)&Ws[cur][r][(quad ^ (r & 7)) * 8];
            bv1[j] = *(const bf16x8*)&Ws[cur][r][((4 + quad) ^ (r & 7)) * 8];
        }
        for (int i = 0; i < MI; i++)
            for (int j = 0; j < NJ; j++) {
                acc[i][j] = MFMA16(a0[i], bv0[j], acc[i][j]);
                acc[i][j] = MFMA16(a1[i], bv1[j], acc[i][j]);
            }
        __syncthreads();
    }

    for (int i = 0; i < MI; i++) {
        const int rbase = m0 + wrow + i * 16 + quad * 4;
        for (int j = 0; j < NJ; j++) {
            const int col = n0 + wcol + j * 16 + l15;
            float bvv = 0.f;
            if constexpr (BIAS) bvv = ((const float*)bias)[col];
            for (int r = 0; r < 4; r++) {
                float v = (acc[i][j][r] + bvv) * scale;
                size_t off = (size_t)(rbase + r) * N + col;
                if constexpr (CF) ((float*)C)[off] = v;
                else              ((__bf16*)C)[off] = (__bf16)v;
            }
        }
    }
}

// ---------------------------------------------------------------------------
// Flash attention, exp2-domain (qp pre-scaled by 0.125*log2e), no online
// rescale (scores bounded ~6 sigma ~ 1.6 << fp32 exp2 overflow at 128).
// 128 q-rows per block x one (b,h); 4 waves x 32 q-rows; K/V chunk = 64.
//
// Round-5: the kernel is LDS-throughput-bound (48 LDS ops/wave-iter ~ 530cy
// x16 iters x16 waves ~ the whole 143k-cyc/CU dispatch; VGPR=72 proves the
// compiler was NOT hoisting loop-invariant fragment reads). Fix: explicitly
// hoist K-fragments (kb, 8 b128) once per iter before the m-loop and
// V-fragments (vb, 8 b128) once before PV -> 48 -> 32 LDS ops/iter. kb/vb
// lifetimes are disjoint (QK vs PV phase) so peak VGPR ~110;
// __launch_bounds__(256,4) pins allocation <=128 to preserve 16 waves/CU
// (R3 lesson: residency loss costs ~18%).
//
// LDS layout (T2): compact 32-elem (64B) rows, 16B-slot XOR swizzle inside
// each 128B row-pair: slot(row,chunk) = ((row&1)*4+chunk) ^ ((row>>1)&7).
// Logical P layout unchanged (sigma contract with vpT). LDS 32KB.
// ---------------------------------------------------------------------------
__device__ __forceinline__ int swz(int row, int chunk) {
    // element offset into a [rows][32] bf16 tile, 16B-slot swizzled
    return (row >> 1) * 64 + (((((row & 1) << 2) | chunk) ^ ((row >> 1) & 7)) << 3);
}

__global__ __launch_bounds__(256, 4) void attn_kernel(
    const __bf16* __restrict__ qp,
    const __bf16* __restrict__ kp,
    const __bf16* __restrict__ vpT,
    __bf16* __restrict__ out)
{
    const int BE = 2048, CK = 1024;
    const int QP = 128 * 32;          // QPs plane stride (elems)
    const int KP = 64 * 32;           // Ks/VTs plane stride

    const int bh = blockIdx.x;       // 0..31 (fast -> all qt of one bh on one XCD)
    const int qt = blockIdx.y;       // 0..31
    const int b = bh >> 3, h = bh & 7;

    __shared__ __attribute__((aligned(16))) __bf16 QPs[2 * 128 * 32]; // Q then P
    __shared__ __attribute__((aligned(16))) __bf16 Ks[2 * 64 * 32];
    __shared__ __attribute__((aligned(16))) __bf16 VTs[2 * 64 * 32];

    const int tid = threadIdx.x;
    const int lane = tid & 63, wv = tid >> 6;
    const int quad = lane >> 4, l15 = lane & 15;

    const size_t ebase = (size_t)b * 512 + h * 64;

    const int srow = tid >> 3;        // 0..31
    const int a8 = (tid & 7) * 8;     // 0..56 (global d-offset)
    const int hp = (tid & 7) >> 2;    // d-half plane select
    const int ch = (tid & 7) & 3;     // 16B chunk within plane

    // stage Q (128 rows x 64 d), hoist this wave's A-frags, then reuse as P
    for (int p = 0; p < 4; p++) {
        bf16x8 v = *(const bf16x8*)&qp[(size_t)(qt * 128 + srow + 32 * p) * BE + ebase + a8];
        *(bf16x8*)&QPs[hp * QP + swz(srow + 32 * p, ch)] = v;
    }
    __syncthreads();
    bf16x8 aq[2][2];
    for (int m = 0; m < 2; m++)
        for (int kk = 0; kk < 2; kk++)
            aq[m][kk] = *(bf16x8*)&QPs[kk * QP + swz(wv * 32 + m * 16 + l15, quad)];

    // preload first K/V chunk into registers
    bf16x8 pk[2], pv[2];
    for (int p = 0; p < 2; p++) {
        pk[p] = *(const bf16x8*)&kp[(size_t)(srow + 32 * p) * BE + ebase + a8];
        pv[p] = *(const bf16x8*)&vpT[((size_t)bh * 64 + srow + 32 * p) * 1024 + a8];
    }

    f32x4 o[2][4];
    for (int m = 0; m < 2; m++)
        for (int dt = 0; dt < 4; dt++) o[m][dt] = (f32x4){0.f, 0.f, 0.f, 0.f};
    float lrowv[2][4] = {{0.f,0.f,0.f,0.f},{0.f,0.f,0.f,0.f}};

    for (int c0 = 0; c0 < CK; c0 += 64) {
        for (int p = 0; p < 2; p++) {
            *(bf16x8*)&Ks[hp * KP + swz(srow + 32 * p, ch)]  = pk[p];
            *(bf16x8*)&VTs[hp * KP + swz(srow + 32 * p, ch)] = pv[p];
        }
        __syncthreads();
        if (c0 + 64 < CK) {
            const int cn = c0 + 64;
            for (int p = 0; p < 2; p++) {
                pk[p] = *(const bf16x8*)&kp[(size_t)(cn + srow + 32 * p) * BE + ebase + a8];
                pv[p] = *(const bf16x8*)&vpT[((size_t)bh * 64 + srow + 32 * p) * 1024 + cn + a8];
            }
        }

        // hoist K fragments ONCE (they are m-invariant; 8 b128 instead of 16)
        bf16x8 kb0[4], kb1[4];
        for (int ct = 0; ct < 4; ct++) {
            kb0[ct] = *(bf16x8*)&Ks[swz(ct * 16 + l15, quad)];
            kb1[ct] = *(bf16x8*)&Ks[KP + swz(ct * 16 + l15, quad)];
        }

        // S = Q K^T, exp2, packed P-stash (wave-private rows of QPs)
        for (int m = 0; m < 2; m++) {
            f32x4 s[4];
            __builtin_amdgcn_s_setprio(1);
            for (int ct = 0; ct < 4; ct++) {
                f32x4 z = (f32x4){0.f, 0.f, 0.f, 0.f};
                z = MFMA16(aq[m][0], kb0[ct], z);
                z = MFMA16(aq[m][1], kb1[ct], z);
                s[ct] = z;
            }
            __builtin_amdgcn_s_setprio(0);
            for (int r = 0; r < 4; r++) {
                bf16x4 pq;
                for (int ct = 0; ct < 4; ct++) {
                    float pp = __builtin_amdgcn_exp2f(s[ct][r]);
                    lrowv[m][r] += pp;
                    pq[ct] = (__bf16)pp;
                }
                // key ct*16+l15 -> sigma position 4*l15+ct:
                // plane l15>>3, chunk (l15&7)>>1, 8B-half l15&1
                *(bf16x4*)&QPs[(l15 >> 3) * QP
                               + swz(wv * 32 + m * 16 + quad * 4 + r, (l15 & 7) >> 1)
                               + (l15 & 1) * 4] = pq;
            }
        }

        // hoist V fragments ONCE (m-invariant; 8 b128 instead of 16).
        // kb dead by here -> kb/vb register lifetimes are disjoint.
        bf16x8 vb[2][4];
        for (int kk = 0; kk < 2; kk++)
            for (int dt = 0; dt < 4; dt++)
                vb[kk][dt] = *(bf16x8*)&VTs[kk * KP + swz(dt * 16 + l15, quad)];

        // O += P @ V   (P reads are same-wave after writes: in-order LDS)
        __builtin_amdgcn_s_setprio(1);
        for (int m = 0; m < 2; m++)
            for (int kk = 0; kk < 2; kk++) {
                bf16x8 ap = *(bf16x8*)&QPs[kk * QP + swz(wv * 32 + m * 16 + l15, quad)];
                for (int dt = 0; dt < 4; dt++)
                    o[m][dt] = MFMA16(ap, vb[kk][dt], o[m][dt]);
            }
        __builtin_amdgcn_s_setprio(0);
        __syncthreads();
    }

    for (int m = 0; m < 2; m++)
        for (int r = 0; r < 4; r++) {
            float l = lrowv[m][r];
            l += __shfl_xor(l, 1);
            l += __shfl_xor(l, 2);
            l += __shfl_xor(l, 4);
            l += __shfl_xor(l, 8);
            const float inv = 1.0f / l;
            const int t = qt * 128 + wv * 32 + m * 16 + quad * 4 + r;
            for (int dt = 0; dt < 4; dt++)
                out[(size_t)t * BE + ebase + dt * 16 + l15] = (__bf16)(o[m][dt][r] * inv);
        }
}

// ---------------------------------------------------------------------------
// Scratch plan. d_out = 32 MiB (fp32 out), ws >= 24 MiB.
//   ws:    [0,16) qT -> dead after s2 -> ao;  [16,20) kin, [20,24) vin
//   d_out: [0,16) qp; [16,24) Wckbf -> kpb/vp; [24,32) Wcvbf -> vpT
// ---------------------------------------------------------------------------
extern "C" void kernel_launch(void* const* d_in, const int* in_sizes, int n_in,
                              void* d_out, int out_size, void* d_ws, size_t ws_size,
                              hipStream_t stream)
{
    const float* query = (const float*)d_in[0];
    const void* Wq = d_in[1];  const void* bq = d_in[2];
    const void* Wk = d_in[3];  const void* bk = d_in[4];
    const void* Wv = d_in[5];  const void* bv = d_in[6];
    const float* Wck = (const float*)d_in[7];
    const float* Wcv = (const float*)d_in[8];
    const void* Wo = d_in[9];  const void* bo = d_in[10];

    const size_t MiB = 1u << 20;

    __bf16* qT    = (__bf16*)d_ws;
    __bf16* kin   = (__bf16*)((char*)d_ws + 16 * MiB);
    __bf16* vin   = (__bf16*)((char*)d_ws + 20 * MiB);
    __bf16* ao    = (__bf16*)d_ws;                       // overlays qT (dead)

    __bf16* qp    = (__bf16*)d_out;
    __bf16* Wckbf = (__bf16*)((char*)d_out + 16 * MiB);
    __bf16* Wcvbf = (__bf16*)((char*)d_out + 24 * MiB);
    __bf16* kpb   = (__bf16*)((char*)d_out + 16 * MiB);  // overlays Wckbf (dead)
    __bf16* vp    = (__bf16*)((char*)d_out + 20 * MiB);
    __bf16* vpT   = (__bf16*)((char*)d_out + 24 * MiB);  // overlays Wcvbf (dead)

    // 0a) Wck/Wcv fp32 -> bf16
    cvt<<<dim3(4096, 2), 256, 0, stream>>>(Wck, Wcv, Wckbf, Wcvbf);
    // 0b) qT = transpose(query) bf16 [2048][4096]
    tq<<<dim3(64, 32), 256, 0, stream>>>(query, qT);

    // 1) qp = (query @ Wq^T + bq) * 0.125 * log2(e)   [16384,512] bf16
    gemm_nt<128, 128, 1, 1, 0, 1><<<dim3(4, 128, 1), 256, 0, stream>>>(
        query, query, Wq, Wq, bq, bq, qp, qp, 16384, 512, 512,
        0.125f * 1.44269504088896f);

    // 2) kin = Wckbf @ qT^T, vin = Wcvbf @ qT^T   [1024,2048] bf16
    gemm_nt<64, 128, 0, 0, 0, 0><<<dim3(16, 16, 2), 256, 0, stream>>>(
        Wckbf, Wcvbf, qT, qT, nullptr, nullptr, kin, vin, 1024, 2048, 4096, 1.0f);

    // 3) kpb = kin @ Wk^T + bk, vp = vin @ Wv^T + bv   [4096,512] bf16
    gemm_nt<64, 128, 0, 1, 0, 1><<<dim3(4, 64, 2), 256, 0, stream>>>(
        kin, vin, Wk, Wv, bk, bv, kpb, vp, 4096, 512, 512, 1.0f);

    // 3b) vpT = sigma-permuted head-transpose(vp)
    tv<<<dim3(16, 32), 256, 0, stream>>>(vp, vpT);

    // 4) attention -> ao bf16 (overlays qT)
    attn_kernel<<<dim3(32, 32), 256, 0, stream>>>(qp, kpb, vpT, ao);

    // 5) out = ao @ Wo^T + bo   fp32, rewrites all of d_out
    gemm_nt<128, 128, 0, 1, 1, 1><<<dim3(4, 128, 1), 256, 0, stream>>>(
        ao, ao, Wo, Wo, bo, bo, d_out, d_out, 16384, 512, 512, 1.0f);
}

// Round 6
// 313.914 us; speedup vs baseline: 1.0472x; 1.0472x over previous
//
#include <hip/hip_runtime.h>

typedef float f32x4 __attribute__((ext_vector_type(4)));
typedef __bf16 bf16x8 __attribute__((ext_vector_type(8)));
typedef __bf16 bf16x4 __attribute__((ext_vector_type(4)));

#define MFMA16(a, b, c) __builtin_amdgcn_mfma_f32_16x16x32_bf16((a), (b), (c), 0, 0, 0)

// Async global->LDS, 16B per lane. Dest is wave-uniform base + lane*16 (linear).
__device__ __forceinline__ void gl16(const void* g, void* l) {
    __builtin_amdgcn_global_load_lds(
        (const __attribute__((address_space(1))) void*)g,
        (__attribute__((address_space(3))) void*)l, 16, 0, 0);
}

// Raw prefetch container (fp32 operands only): keep fp32 loads unconverted so
// the cvt (and its waitcnt) lands at LDS-write time, a full iteration later.
template<int F> struct Raw;
template<> struct Raw<0> { bf16x8 v; };
template<> struct Raw<1> { f32x4 a, b; };

template<int F>
__device__ __forceinline__ Raw<F> ldraw(const void* p, size_t idx) {
    Raw<F> r;
    if constexpr (F) {
        const float* q = (const float*)p + idx;
        r.a = *(const f32x4*)q;
        r.b = *(const f32x4*)(q + 4);
    } else {
        r.v = *(const bf16x8*)((const __bf16*)p + idx);
    }
    return r;
}
template<int F>
__device__ __forceinline__ bf16x8 toBf(const Raw<F>& r) {
    if constexpr (F) {
        bf16x8 o;
        o[0] = (__bf16)r.a[0]; o[1] = (__bf16)r.a[1]; o[2] = (__bf16)r.a[2]; o[3] = (__bf16)r.a[3];
        o[4] = (__bf16)r.b[0]; o[5] = (__bf16)r.b[1]; o[6] = (__bf16)r.b[2]; o[7] = (__bf16)r.b[3];
        return o;
    } else {
        return r.v;
    }
}

// ---------------------------------------------------------------------------
// cvt: fp32 -> bf16 bulk convert (Wck / Wcv).
// ---------------------------------------------------------------------------
__global__ __launch_bounds__(256) void cvt(
    const float* __restrict__ a0, const float* __restrict__ a1,
    __bf16* __restrict__ o0, __bf16* __restrict__ o1)
{
    const float* a = blockIdx.y ? a1 : a0;
    __bf16* o = blockIdx.y ? o1 : o0;
    size_t i = ((size_t)blockIdx.x * 256 + threadIdx.x) * 4;
    f32x4 v = *(const f32x4*)&a[i];
    bf16x4 r; r[0]=(__bf16)v[0]; r[1]=(__bf16)v[1]; r[2]=(__bf16)v[2]; r[3]=(__bf16)v[3];
    *(bf16x4*)&o[i] = r;
}

// ---------------------------------------------------------------------------
// tq: query fp32 [4096 t][2048 n] -> qT bf16 [2048 n][4096 t].
// ---------------------------------------------------------------------------
__global__ __launch_bounds__(256) void tq(
    const float* __restrict__ q, __bf16* __restrict__ qT)
{
    __shared__ float Ts[64][65];
    const int t0 = blockIdx.x * 64, n0 = blockIdx.y * 64;
    const int tid = threadIdx.x;
    const int r = tid >> 4, c4 = (tid & 15) * 4;
    for (int p = 0; p < 4; p++) {
        f32x4 v = *(const f32x4*)&q[(size_t)(t0 + r + 16 * p) * 2048 + n0 + c4];
        Ts[r + 16 * p][c4 + 0] = v[0];
        Ts[r + 16 * p][c4 + 1] = v[1];
        Ts[r + 16 * p][c4 + 2] = v[2];
        Ts[r + 16 * p][c4 + 3] = v[3];
    }
    __syncthreads();
    for (int p = 0; p < 4; p++) {
        const int nrow = r + 16 * p;
        bf16x4 o;
        o[0] = (__bf16)Ts[c4 + 0][nrow];
        o[1] = (__bf16)Ts[c4 + 1][nrow];
        o[2] = (__bf16)Ts[c4 + 2][nrow];
        o[3] = (__bf16)Ts[c4 + 3][nrow];
        *(bf16x4*)&qT[(size_t)(n0 + nrow) * 4096 + t0 + c4] = o;
    }
}

// ---------------------------------------------------------------------------
// tv: vp bf16 [4096 (4c+b)][512 (64h+d)] -> vpT bf16 [32 bh][64 d][1024 c'],
// with c' sigma-permuted inside each 64-block: sigma(cc)=4*(cc&15)+(cc>>4).
// ---------------------------------------------------------------------------
__global__ __launch_bounds__(256) void tv(
    const __bf16* __restrict__ vp, __bf16* __restrict__ vpT)
{
    __shared__ __bf16 Ts[64][72];   // [cc][d]
    const int c0 = blockIdx.x * 64;
    const int bh = blockIdx.y, b = bh >> 3, h = bh & 7;
    const int tid = threadIdx.x;
    const int cr = tid >> 3, a8 = (tid & 7) * 8;
    for (int p = 0; p < 2; p++) {
        bf16x8 v = *(const bf16x8*)&vp[(size_t)(4 * (c0 + cr + 32 * p) + b) * 512 + h * 64 + a8];
        *(bf16x8*)&Ts[cr + 32 * p][a8] = v;
    }
    __syncthreads();
    for (int p = 0; p < 2; p++) {
        const int d = cr + 32 * p;
        bf16x8 o;
        for (int u = 0; u < 8; u++) {
            const int pos = a8 + u;                       // permuted position
            const int cc = (pos & 3) * 16 + (pos >> 2);   // source key index
            o[u] = Ts[cc][d];
        }
        *(bf16x8*)&vpT[((size_t)bh * 64 + d) * 1024 + c0 + a8] = o;
    }
}

// ---------------------------------------------------------------------------
// NT GEMM: C = (A @ W^T + bias) * scale.  A:[M,K], W:[N,K] rm.
// BK=64, double-buffered LDS, ONE barrier per K-step. BN=128 config is the
// measured optimum (R4's BN=64 doubled A-panel re-fetch -> +25us).
// Swizzle: slot (r, chunk j) holds logical chunk j ^ (r&7); both-sides
// (pre-swizzled gload source / swizzled ds_write + swizzled read).
// ---------------------------------------------------------------------------
template<int BM, int BN, int AF, int WF, int CF, int BIAS>
__global__ __launch_bounds__(256) void gemm_nt(
    const void* __restrict__ A0, const void* __restrict__ A1,
    const void* __restrict__ W0, const void* __restrict__ W1,
    const void* __restrict__ b0, const void* __restrict__ b1,
    void* __restrict__ C0, void* __restrict__ C1,
    int M, int N, int K, float scale)
{
    const void* A = blockIdx.z ? A1 : A0;
    const void* W = blockIdx.z ? W1 : W0;
    const void* bias = blockIdx.z ? b1 : b0;
    void* C = blockIdx.z ? C1 : C0;

    __shared__ __attribute__((aligned(16))) __bf16 As[2][BM][64];
    __shared__ __attribute__((aligned(16))) __bf16 Ws[2][BN][64];

    const int n0 = blockIdx.x * BN;
    const int m0 = blockIdx.y * BM;
    const int tid = threadIdx.x;
    const int lane = tid & 63, wv = tid >> 6;
    const int quad = lane >> 4, l15 = lane & 15;
    constexpr int WR = BM / 2, MI = WR / 16;
    constexpr int WC = BN / 2, NJ = WC / 16;
    const int wrow = (wv >> 1) * WR, wcol = (wv & 1) * WC;

    // gload_lds geometry: one instr = 8 rows x 128B, dest linear from a
    // wave-uniform base. Lane l lands at (row base+l>>3, chunk l&7); to build
    // the swizzled layout it loads global chunk (l&7) ^ (l>>3).
    const int lrow = lane >> 3;
    const int csrc = ((lane & 7) ^ lrow) * 8;   // source chunk, in elements

    // fp32 reg-staging geometry: thread handles (row tid>>3 + 32p, chunk tid&7),
    // written to the swizzled slot so reads are layout-identical to gload path.
    const int srow = tid >> 3;
    const int sj = tid & 7;
    const int swc = (sj ^ (srow & 7)) * 8;      // swizzled dest column

    constexpr int AP = BM / 32;
    constexpr int WP = BN / 32;
    Raw<AF> pa[AP];
    Raw<WF> pw[WP];

    auto stageA = [&](int buf, int kt) {
        if constexpr (AF == 0) {
            for (int p = 0; p < AP; p++)
                gl16((const __bf16*)A + (size_t)(m0 + wv * 8 + p * 32 + lrow) * K + kt + csrc,
                     &As[buf][wv * 8 + p * 32][0]);
        } else {
            (void)kt;
            for (int p = 0; p < AP; p++)
                *(bf16x8*)&As[buf][srow + 32 * p][swc] = toBf<AF>(pa[p]);
        }
    };
    auto stageW = [&](int buf, int kt) {
        if constexpr (WF == 0) {
            for (int p = 0; p < WP; p++)
                gl16((const __bf16*)W + (size_t)(n0 + wv * 8 + p * 32 + lrow) * K + kt + csrc,
                     &Ws[buf][wv * 8 + p * 32][0]);
        } else {
            (void)kt;
            for (int p = 0; p < WP; p++)
                *(bf16x8*)&Ws[buf][srow + 32 * p][swc] = toBf<WF>(pw[p]);
        }
    };
    auto loadA = [&](int kt) {
        if constexpr (AF == 1)
            for (int p = 0; p < AP; p++)
                pa[p] = ldraw<AF>(A, (size_t)(m0 + srow + 32 * p) * K + kt + sj * 8);
    };
    auto loadW = [&](int kt) {
        if constexpr (WF == 1)
            for (int p = 0; p < WP; p++)
                pw[p] = ldraw<WF>(W, (size_t)(n0 + srow + 32 * p) * K + kt + sj * 8);
    };

    f32x4 acc[MI][NJ];
    for (int i = 0; i < MI; i++)
        for (int j = 0; j < NJ; j++)
            acc[i][j] = (f32x4){0.f, 0.f, 0.f, 0.f};

    // prologue: tile 0 -> buf 0; fp32 operands additionally prefetch tile 1
    loadA(0);
    loadW(0);
    stageA(0, 0);
    stageW(0, 0);
    loadA(64);
    loadW(64);
    __syncthreads();

    const int NT = K >> 6;
    for (int t = 0; t < NT; ++t) {
        const int cur = t & 1;
        if (t + 1 < NT) {
            stageA(cur ^ 1, (t + 1) * 64);   // fp32 path: writes pregs (tile t+1)
            stageW(cur ^ 1, (t + 1) * 64);
            if (t + 2 < NT) { loadA((t + 2) * 64); loadW((t + 2) * 64); }
        }
        bf16x8 a0[MI], a1[MI], bv0[NJ], bv1[NJ];
        for (int i = 0; i < MI; i++) {
            const int r = wrow + i * 16 + l15;
            a0[i] = *(const bf16x8*)&As[cur][r][(quad ^ (r & 7)) * 8];
            a1[i] = *(const bf16x8*)&As[cur][r][((4 + quad) ^ (r & 7)) * 8];
        }
        for (int j = 0; j < NJ; j++) {
            const int r = wcol + j * 16 + l15;
            bv0[j] = *(const bf16x8*)&Ws[cur][r][(quad ^ (r & 7)) * 8];
            bv1[j] = *(const bf16x8*)&Ws[cur][r][((4 + quad) ^ (r & 7)) * 8];
        }
        for (int i = 0; i < MI; i++)
            for (int j = 0; j < NJ; j++) {
                acc[i][j] = MFMA16(a0[i], bv0[j], acc[i][j]);
                acc[i][j] = MFMA16(a1[i], bv1[j], acc[i][j]);
            }
        __syncthreads();
    }

    for (int i = 0; i < MI; i++) {
        const int rbase = m0 + wrow + i * 16 + quad * 4;
        for (int j = 0; j < NJ; j++) {
            const int col = n0 + wcol + j * 16 + l15;
            float bvv = 0.f;
            if constexpr (BIAS) bvv = ((const float*)bias)[col];
            for (int r = 0; r < 4; r++) {
                float v = (acc[i][j][r] + bvv) * scale;
                size_t off = (size_t)(rbase + r) * N + col;
                if constexpr (CF) ((float*)C)[off] = v;
                else              ((__bf16*)C)[off] = (__bf16)v;
            }
        }
    }
}

// ---------------------------------------------------------------------------
// Flash attention, exp2-domain (qp pre-scaled by 0.125*log2e), no online
// rescale (scores bounded ~6 sigma ~ 1.6 << fp32 exp2 overflow at 128).
// 128 q-rows per block x one (b,h); 4 waves x 32 q-rows; K/V chunk = 64.
//
// Round-6: LDS-throughput-bound (48 b128-class ops/wave-iter x 16 waves x
// ~12cy ~ 123k of the 143k cyc/CU). R5's full kb+vb hoist hit the 128-VGPR
// cap and spilled (WRITE_SIZE 16MB -> 254MB, scratch). This round keeps the
// same op-count cut (48 -> 32/iter) at ~24 fewer peak regs:
//   - kb0/kb1 hoist (+32 VGPR, live only in QK phase): QK reads 16 -> 8
//   - PV reordered kk-outer, vb[4] hoisted per kk (+16 VGPR, PV phase only):
//     PV reads 20 -> 12. Accumulation chain per o[m][dt] unchanged (kk0->kk1).
// Est. peak ~104-110 < 128; __launch_bounds__(256,4) guards the occupancy
// cliff (129+ VGPR -> 2 waves/SIMD). Go/no-go next round: WRITE_SIZE must
// be 16384 KB (no scratch).
//
// LDS layout (T2): compact 32-elem (64B) rows, 16B-slot XOR swizzle inside
// each 128B row-pair: slot(row,chunk) = ((row&1)*4+chunk) ^ ((row>>1)&7).
// Logical P layout unchanged (sigma contract with vpT). LDS 32KB.
// ---------------------------------------------------------------------------
__device__ __forceinline__ int swz(int row, int chunk) {
    // element offset into a [rows][32] bf16 tile, 16B-slot swizzled
    return (row >> 1) * 64 + (((((row & 1) << 2) | chunk) ^ ((row >> 1) & 7)) << 3);
}

__global__ __launch_bounds__(256, 4) void attn_kernel(
    const __bf16* __restrict__ qp,
    const __bf16* __restrict__ kp,
    const __bf16* __restrict__ vpT,
    __bf16* __restrict__ out)
{
    const int BE = 2048, CK = 1024;
    const int QP = 128 * 32;          // QPs plane stride (elems)
    const int KP = 64 * 32;           // Ks/VTs plane stride

    const int bh = blockIdx.x;       // 0..31 (fast -> K/V L2 locality per XCD)
    const int qt = blockIdx.y;       // 0..31
    const int b = bh >> 3, h = bh & 7;

    __shared__ __attribute__((aligned(16))) __bf16 QPs[2 * 128 * 32]; // Q then P
    __shared__ __attribute__((aligned(16))) __bf16 Ks[2 * 64 * 32];
    __shared__ __attribute__((aligned(16))) __bf16 VTs[2 * 64 * 32];

    const int tid = threadIdx.x;
    const int lane = tid & 63, wv = tid >> 6;
    const int quad = lane >> 4, l15 = lane & 15;

    const size_t ebase = (size_t)b * 512 + h * 64;

    const int srow = tid >> 3;        // 0..31
    const int a8 = (tid & 7) * 8;     // 0..56 (global d-offset)
    const int hp = (tid & 7) >> 2;    // d-half plane select
    const int ch = (tid & 7) & 3;     // 16B chunk within plane

    // stage Q (128 rows x 64 d), hoist this wave's A-frags, then reuse as P
    for (int p = 0; p < 4; p++) {
        bf16x8 v = *(const bf16x8*)&qp[(size_t)(qt * 128 + srow + 32 * p) * BE + ebase + a8];
        *(bf16x8*)&QPs[hp * QP + swz(srow + 32 * p, ch)] = v;
    }
    __syncthreads();
    bf16x8 aq[2][2];
    for (int m = 0; m < 2; m++)
        for (int kk = 0; kk < 2; kk++)
            aq[m][kk] = *(bf16x8*)&QPs[kk * QP + swz(wv * 32 + m * 16 + l15, quad)];

    // preload first K/V chunk into registers
    bf16x8 pk[2], pv[2];
    for (int p = 0; p < 2; p++) {
        pk[p] = *(const bf16x8*)&kp[(size_t)(srow + 32 * p) * BE + ebase + a8];
        pv[p] = *(const bf16x8*)&vpT[((size_t)bh * 64 + srow + 32 * p) * 1024 + a8];
    }

    f32x4 o[2][4];
    for (int m = 0; m < 2; m++)
        for (int dt = 0; dt < 4; dt++) o[m][dt] = (f32x4){0.f, 0.f, 0.f, 0.f};
    float lrowv[2][4] = {{0.f,0.f,0.f,0.f},{0.f,0.f,0.f,0.f}};

    for (int c0 = 0; c0 < CK; c0 += 64) {
        for (int p = 0; p < 2; p++) {
            *(bf16x8*)&Ks[hp * KP + swz(srow + 32 * p, ch)]  = pk[p];
            *(bf16x8*)&VTs[hp * KP + swz(srow + 32 * p, ch)] = pv[p];
        }
        __syncthreads();
        if (c0 + 64 < CK) {
            const int cn = c0 + 64;
            for (int p = 0; p < 2; p++) {
                pk[p] = *(const bf16x8*)&kp[(size_t)(cn + srow + 32 * p) * BE + ebase + a8];
                pv[p] = *(const bf16x8*)&vpT[((size_t)bh * 64 + srow + 32 * p) * 1024 + cn + a8];
            }
        }

        // hoist K fragments ONCE (m-invariant): 8 b128 instead of 16.
        // Live only during the QK phase (+32 VGPR here, dead before vb).
        bf16x8 kb0[4], kb1[4];
        for (int ct = 0; ct < 4; ct++) {
            kb0[ct] = *(bf16x8*)&Ks[swz(ct * 16 + l15, quad)];
            kb1[ct] = *(bf16x8*)&Ks[KP + swz(ct * 16 + l15, quad)];
        }

        // S = Q K^T, exp2, packed P-stash (wave-private rows of QPs)
        for (int m = 0; m < 2; m++) {
            f32x4 s[4];
            __builtin_amdgcn_s_setprio(1);
            for (int ct = 0; ct < 4; ct++) {
                f32x4 z = (f32x4){0.f, 0.f, 0.f, 0.f};
                z = MFMA16(aq[m][0], kb0[ct], z);
                z = MFMA16(aq[m][1], kb1[ct], z);
                s[ct] = z;
            }
            __builtin_amdgcn_s_setprio(0);
            for (int r = 0; r < 4; r++) {
                bf16x4 pq;
                for (int ct = 0; ct < 4; ct++) {
                    float pp = __builtin_amdgcn_exp2f(s[ct][r]);
                    lrowv[m][r] += pp;
                    pq[ct] = (__bf16)pp;
                }
                // key ct*16+l15 -> sigma position 4*l15+ct:
                // plane l15>>3, chunk (l15&7)>>1, 8B-half l15&1
                *(bf16x4*)&QPs[(l15 >> 3) * QP
                               + swz(wv * 32 + m * 16 + quad * 4 + r, (l15 & 7) >> 1)
                               + (l15 & 1) * 4] = pq;
            }
        }

        // O += P @ V, kk-outer with per-kk vb hoist (+16 VGPR, PV phase only):
        // reads 12 b128/iter instead of 20. o[m][dt] still accumulates
        // kk0 -> kk1 (same chain as before).
        __builtin_amdgcn_s_setprio(1);
        for (int kk = 0; kk < 2; kk++) {
            bf16x8 vb[4];
            for (int dt = 0; dt < 4; dt++)
                vb[dt] = *(bf16x8*)&VTs[kk * KP + swz(dt * 16 + l15, quad)];
            for (int m = 0; m < 2; m++) {
                bf16x8 ap = *(bf16x8*)&QPs[kk * QP + swz(wv * 32 + m * 16 + l15, quad)];
                for (int dt = 0; dt < 4; dt++)
                    o[m][dt] = MFMA16(ap, vb[dt], o[m][dt]);
            }
        }
        __builtin_amdgcn_s_setprio(0);
        __syncthreads();
    }

    for (int m = 0; m < 2; m++)
        for (int r = 0; r < 4; r++) {
            float l = lrowv[m][r];
            l += __shfl_xor(l, 1);
            l += __shfl_xor(l, 2);
            l += __shfl_xor(l, 4);
            l += __shfl_xor(l, 8);
            const float inv = 1.0f / l;
            const int t = qt * 128 + wv * 32 + m * 16 + quad * 4 + r;
            for (int dt = 0; dt < 4; dt++)
                out[(size_t)t * BE + ebase + dt * 16 + l15] = (__bf16)(o[m][dt][r] * inv);
        }
}

// ---------------------------------------------------------------------------
// Scratch plan. d_out = 32 MiB (fp32 out), ws >= 24 MiB.
//   ws:    [0,16) qT -> dead after s2 -> ao;  [16,20) kin, [20,24) vin
//   d_out: [0,16) qp; [16,24) Wckbf -> kpb/vp; [24,32) Wcvbf -> vpT
// ---------------------------------------------------------------------------
extern "C" void kernel_launch(void* const* d_in, const int* in_sizes, int n_in,
                              void* d_out, int out_size, void* d_ws, size_t ws_size,
                              hipStream_t stream)
{
    const float* query = (const float*)d_in[0];
    const void* Wq = d_in[1];  const void* bq = d_in[2];
    const void* Wk = d_in[3];  const void* bk = d_in[4];
    const void* Wv = d_in[5];  const void* bv = d_in[6];
    const float* Wck = (const float*)d_in[7];
    const float* Wcv = (const float*)d_in[8];
    const void* Wo = d_in[9];  const void* bo = d_in[10];

    const size_t MiB = 1u << 20;

    __bf16* qT    = (__bf16*)d_ws;
    __bf16* kin   = (__bf16*)((char*)d_ws + 16 * MiB);
    __bf16* vin   = (__bf16*)((char*)d_ws + 20 * MiB);
    __bf16* ao    = (__bf16*)d_ws;                       // overlays qT (dead)

    __bf16* qp    = (__bf16*)d_out;
    __bf16* Wckbf = (__bf16*)((char*)d_out + 16 * MiB);
    __bf16* Wcvbf = (__bf16*)((char*)d_out + 24 * MiB);
    __bf16* kpb   = (__bf16*)((char*)d_out + 16 * MiB);  // overlays Wckbf (dead)
    __bf16* vp    = (__bf16*)((char*)d_out + 20 * MiB);
    __bf16* vpT   = (__bf16*)((char*)d_out + 24 * MiB);  // overlays Wcvbf (dead)

    // 0a) Wck/Wcv fp32 -> bf16
    cvt<<<dim3(4096, 2), 256, 0, stream>>>(Wck, Wcv, Wckbf, Wcvbf);
    // 0b) qT = transpose(query) bf16 [2048][4096]
    tq<<<dim3(64, 32), 256, 0, stream>>>(query, qT);

    // 1) qp = (query @ Wq^T + bq) * 0.125 * log2(e)   [16384,512] bf16
    gemm_nt<128, 128, 1, 1, 0, 1><<<dim3(4, 128, 1), 256, 0, stream>>>(
        query, query, Wq, Wq, bq, bq, qp, qp, 16384, 512, 512,
        0.125f * 1.44269504088896f);

    // 2) kin = Wckbf @ qT^T, vin = Wcvbf @ qT^T   [1024,2048] bf16
    gemm_nt<64, 128, 0, 0, 0, 0><<<dim3(16, 16, 2), 256, 0, stream>>>(
        Wckbf, Wcvbf, qT, qT, nullptr, nullptr, kin, vin, 1024, 2048, 4096, 1.0f);

    // 3) kpb = kin @ Wk^T + bk, vp = vin @ Wv^T + bv   [4096,512] bf16
    gemm_nt<64, 128, 0, 1, 0, 1><<<dim3(4, 64, 2), 256, 0, stream>>>(
        kin, vin, Wk, Wv, bk, bv, kpb, vp, 4096, 512, 512, 1.0f);

    // 3b) vpT = sigma-permuted head-transpose(vp)
    tv<<<dim3(16, 32), 256, 0, stream>>>(vp, vpT);

    // 4) attention -> ao bf16 (overlays qT)
    attn_kernel<<<dim3(32, 32), 256, 0, stream>>>(qp, kpb, vpT, ao);

    // 5) out = ao @ Wo^T + bo   fp32, rewrites all of d_out
    gemm_nt<128, 128, 0, 1, 1, 1><<<dim3(4, 128, 1), 256, 0, stream>>>(
        ao, ao, Wo, Wo, bo, bo, d_out, d_out, 16384, 512, 512, 1.0f);
}

// Round 7
// 290.826 us; speedup vs baseline: 1.1303x; 1.0794x over previous
//
#include <hip/hip_runtime.h>

typedef float f32x4 __attribute__((ext_vector_type(4)));
typedef __bf16 bf16x8 __attribute__((ext_vector_type(8)));
typedef __bf16 bf16x4 __attribute__((ext_vector_type(4)));

#define MFMA16(a, b, c) __builtin_amdgcn_mfma_f32_16x16x32_bf16((a), (b), (c), 0, 0, 0)

// Async global->LDS, 16B per lane. Dest is wave-uniform base + lane*16 (linear).
__device__ __forceinline__ void gl16(const void* g, void* l) {
    __builtin_amdgcn_global_load_lds(
        (const __attribute__((address_space(1))) void*)g,
        (__attribute__((address_space(3))) void*)l, 16, 0, 0);
}

// Raw prefetch container (fp32 operands only): keep fp32 loads unconverted so
// the cvt (and its waitcnt) lands at LDS-write time, a full iteration later.
template<int F> struct Raw;
template<> struct Raw<0> { bf16x8 v; };
template<> struct Raw<1> { f32x4 a, b; };

template<int F>
__device__ __forceinline__ Raw<F> ldraw(const void* p, size_t idx) {
    Raw<F> r;
    if constexpr (F) {
        const float* q = (const float*)p + idx;
        r.a = *(const f32x4*)q;
        r.b = *(const f32x4*)(q + 4);
    } else {
        r.v = *(const bf16x8*)((const __bf16*)p + idx);
    }
    return r;
}
template<int F>
__device__ __forceinline__ bf16x8 toBf(const Raw<F>& r) {
    if constexpr (F) {
        bf16x8 o;
        o[0] = (__bf16)r.a[0]; o[1] = (__bf16)r.a[1]; o[2] = (__bf16)r.a[2]; o[3] = (__bf16)r.a[3];
        o[4] = (__bf16)r.b[0]; o[5] = (__bf16)r.b[1]; o[6] = (__bf16)r.b[2]; o[7] = (__bf16)r.b[3];
        return o;
    } else {
        return r.v;
    }
}

// ---------------------------------------------------------------------------
// cvt: fp32 -> bf16 bulk convert (Wck / Wcv).
// ---------------------------------------------------------------------------
__global__ __launch_bounds__(256) void cvt(
    const float* __restrict__ a0, const float* __restrict__ a1,
    __bf16* __restrict__ o0, __bf16* __restrict__ o1)
{
    const float* a = blockIdx.y ? a1 : a0;
    __bf16* o = blockIdx.y ? o1 : o0;
    size_t i = ((size_t)blockIdx.x * 256 + threadIdx.x) * 4;
    f32x4 v = *(const f32x4*)&a[i];
    bf16x4 r; r[0]=(__bf16)v[0]; r[1]=(__bf16)v[1]; r[2]=(__bf16)v[2]; r[3]=(__bf16)v[3];
    *(bf16x4*)&o[i] = r;
}

// ---------------------------------------------------------------------------
// tq: query fp32 [4096 t][2048 n] -> qT bf16 [2048 n][4096 t].
// ---------------------------------------------------------------------------
__global__ __launch_bounds__(256) void tq(
    const float* __restrict__ q, __bf16* __restrict__ qT)
{
    __shared__ float Ts[64][65];
    const int t0 = blockIdx.x * 64, n0 = blockIdx.y * 64;
    const int tid = threadIdx.x;
    const int r = tid >> 4, c4 = (tid & 15) * 4;
    for (int p = 0; p < 4; p++) {
        f32x4 v = *(const f32x4*)&q[(size_t)(t0 + r + 16 * p) * 2048 + n0 + c4];
        Ts[r + 16 * p][c4 + 0] = v[0];
        Ts[r + 16 * p][c4 + 1] = v[1];
        Ts[r + 16 * p][c4 + 2] = v[2];
        Ts[r + 16 * p][c4 + 3] = v[3];
    }
    __syncthreads();
    for (int p = 0; p < 4; p++) {
        const int nrow = r + 16 * p;
        bf16x4 o;
        o[0] = (__bf16)Ts[c4 + 0][nrow];
        o[1] = (__bf16)Ts[c4 + 1][nrow];
        o[2] = (__bf16)Ts[c4 + 2][nrow];
        o[3] = (__bf16)Ts[c4 + 3][nrow];
        *(bf16x4*)&qT[(size_t)(n0 + nrow) * 4096 + t0 + c4] = o;
    }
}

// ---------------------------------------------------------------------------
// tv: vp bf16 [4096 (4c+b)][512 (64h+d)] -> vpT bf16 [32 bh][64 d][1024 c'],
// with c' sigma-permuted inside each 64-block: sigma(cc)=4*(cc&15)+(cc>>4).
// ---------------------------------------------------------------------------
__global__ __launch_bounds__(256) void tv(
    const __bf16* __restrict__ vp, __bf16* __restrict__ vpT)
{
    __shared__ __bf16 Ts[64][72];   // [cc][d]
    const int c0 = blockIdx.x * 64;
    const int bh = blockIdx.y, b = bh >> 3, h = bh & 7;
    const int tid = threadIdx.x;
    const int cr = tid >> 3, a8 = (tid & 7) * 8;
    for (int p = 0; p < 2; p++) {
        bf16x8 v = *(const bf16x8*)&vp[(size_t)(4 * (c0 + cr + 32 * p) + b) * 512 + h * 64 + a8];
        *(bf16x8*)&Ts[cr + 32 * p][a8] = v;
    }
    __syncthreads();
    for (int p = 0; p < 2; p++) {
        const int d = cr + 32 * p;
        bf16x8 o;
        for (int u = 0; u < 8; u++) {
            const int pos = a8 + u;                       // permuted position
            const int cc = (pos & 3) * 16 + (pos >> 2);   // source key index
            o[u] = Ts[cc][d];
        }
        *(bf16x8*)&vpT[((size_t)bh * 64 + d) * 1024 + c0 + a8] = o;
    }
}

// ---------------------------------------------------------------------------
// NT GEMM: C = (A @ W^T + bias) * scale.  A:[M,K], W:[N,K] rm.
// BK=64, double-buffered LDS, ONE barrier per K-step. BN=128 config is the
// measured optimum (R4's BN=64 doubled A-panel re-fetch -> +25us).
// Swizzle: slot (r, chunk j) holds logical chunk j ^ (r&7); both-sides
// (pre-swizzled gload source / swizzled ds_write + swizzled read).
// ---------------------------------------------------------------------------
template<int BM, int BN, int AF, int WF, int CF, int BIAS>
__global__ __launch_bounds__(256) void gemm_nt(
    const void* __restrict__ A0, const void* __restrict__ A1,
    const void* __restrict__ W0, const void* __restrict__ W1,
    const void* __restrict__ b0, const void* __restrict__ b1,
    void* __restrict__ C0, void* __restrict__ C1,
    int M, int N, int K, float scale)
{
    const void* A = blockIdx.z ? A1 : A0;
    const void* W = blockIdx.z ? W1 : W0;
    const void* bias = blockIdx.z ? b1 : b0;
    void* C = blockIdx.z ? C1 : C0;

    __shared__ __attribute__((aligned(16))) __bf16 As[2][BM][64];
    __shared__ __attribute__((aligned(16))) __bf16 Ws[2][BN][64];

    const int n0 = blockIdx.x * BN;
    const int m0 = blockIdx.y * BM;
    const int tid = threadIdx.x;
    const int lane = tid & 63, wv = tid >> 6;
    const int quad = lane >> 4, l15 = lane & 15;
    constexpr int WR = BM / 2, MI = WR / 16;
    constexpr int WC = BN / 2, NJ = WC / 16;
    const int wrow = (wv >> 1) * WR, wcol = (wv & 1) * WC;

    // gload_lds geometry: one instr = 8 rows x 128B, dest linear from a
    // wave-uniform base. Lane l lands at (row base+l>>3, chunk l&7); to build
    // the swizzled layout it loads global chunk (l&7) ^ (l>>3).
    const int lrow = lane >> 3;
    const int csrc = ((lane & 7) ^ lrow) * 8;   // source chunk, in elements

    // fp32 reg-staging geometry: thread handles (row tid>>3 + 32p, chunk tid&7),
    // written to the swizzled slot so reads are layout-identical to gload path.
    const int srow = tid >> 3;
    const int sj = tid & 7;
    const int swc = (sj ^ (srow & 7)) * 8;      // swizzled dest column

    constexpr int AP = BM / 32;
    constexpr int WP = BN / 32;
    Raw<AF> pa[AP];
    Raw<WF> pw[WP];

    auto stageA = [&](int buf, int kt) {
        if constexpr (AF == 0) {
            for (int p = 0; p < AP; p++)
                gl16((const __bf16*)A + (size_t)(m0 + wv * 8 + p * 32 + lrow) * K + kt + csrc,
                     &As[buf][wv * 8 + p * 32][0]);
        } else {
            (void)kt;
            for (int p = 0; p < AP; p++)
                *(bf16x8*)&As[buf][srow + 32 * p][swc] = toBf<AF>(pa[p]);
        }
    };
    auto stageW = [&](int buf, int kt) {
        if constexpr (WF == 0) {
            for (int p = 0; p < WP; p++)
                gl16((const __bf16*)W + (size_t)(n0 + wv * 8 + p * 32 + lrow) * K + kt + csrc,
                     &Ws[buf][wv * 8 + p * 32][0]);
        } else {
            (void)kt;
            for (int p = 0; p < WP; p++)
                *(bf16x8*)&Ws[buf][srow + 32 * p][swc] = toBf<WF>(pw[p]);
        }
    };
    auto loadA = [&](int kt) {
        if constexpr (AF == 1)
            for (int p = 0; p < AP; p++)
                pa[p] = ldraw<AF>(A, (size_t)(m0 + srow + 32 * p) * K + kt + sj * 8);
    };
    auto loadW = [&](int kt) {
        if constexpr (WF == 1)
            for (int p = 0; p < WP; p++)
                pw[p] = ldraw<WF>(W, (size_t)(n0 + srow + 32 * p) * K + kt + sj * 8);
    };

    f32x4 acc[MI][NJ];
    for (int i = 0; i < MI; i++)
        for (int j = 0; j < NJ; j++)
            acc[i][j] = (f32x4){0.f, 0.f, 0.f, 0.f};

    // prologue: tile 0 -> buf 0; fp32 operands additionally prefetch tile 1
    loadA(0);
    loadW(0);
    stageA(0, 0);
    stageW(0, 0);
    loadA(64);
    loadW(64);
    __syncthreads();

    const int NT = K >> 6;
    for (int t = 0; t < NT; ++t) {
        const int cur = t & 1;
        if (t + 1 < NT) {
            stageA(cur ^ 1, (t + 1) * 64);   // fp32 path: writes pregs (tile t+1)
            stageW(cur ^ 1, (t + 1) * 64);
            if (t + 2 < NT) { loadA((t + 2) * 64); loadW((t + 2) * 64); }
        }
        bf16x8 a0[MI], a1[MI], bv0[NJ], bv1[NJ];
        for (int i = 0; i < MI; i++) {
            const int r = wrow + i * 16 + l15;
            a0[i] = *(const bf16x8*)&As[cur][r][(quad ^ (r & 7)) * 8];
            a1[i] = *(const bf16x8*)&As[cur][r][((4 + quad) ^ (r & 7)) * 8];
        }
        for (int j = 0; j < NJ; j++) {
            const int r = wcol + j * 16 + l15;
            bv0[j] = *(const bf16x8*)&Ws[cur][r][(quad ^ (r & 7)) * 8];
            bv1[j] = *(const bf16x8*)&Ws[cur][r][((4 + quad) ^ (r & 7)) * 8];
        }
        for (int i = 0; i < MI; i++)
            for (int j = 0; j < NJ; j++) {
                acc[i][j] = MFMA16(a0[i], bv0[j], acc[i][j]);
                acc[i][j] = MFMA16(a1[i], bv1[j], acc[i][j]);
            }
        __syncthreads();
    }

    for (int i = 0; i < MI; i++) {
        const int rbase = m0 + wrow + i * 16 + quad * 4;
        for (int j = 0; j < NJ; j++) {
            const int col = n0 + wcol + j * 16 + l15;
            float bvv = 0.f;
            if constexpr (BIAS) bvv = ((const float*)bias)[col];
            for (int r = 0; r < 4; r++) {
                float v = (acc[i][j][r] + bvv) * scale;
                size_t off = (size_t)(rbase + r) * N + col;
                if constexpr (CF) ((float*)C)[off] = v;
                else              ((__bf16*)C)[off] = (__bf16)v;
            }
        }
    }
}

// ---------------------------------------------------------------------------
// Flash attention, exp2-domain (qp pre-scaled by 0.125*log2e), no online
// rescale (scores bounded ~6 sigma ~ 1.6 << fp32 exp2 overflow at 128).
// 128 q-rows per block x one (b,h); 4 waves x 32 q-rows; K/V chunk = 64.
//
// Round-7: EXACT R2 structure (59.6us, VGPR 72, no spill) with ONE delta:
// PV reordered kk-outer with vb[4] hoisted per kk (+16 VGPR, PV phase only)
// -> PV LDS reads 20 -> 12 b128/iter (total 48 -> 40 ops on the ~80%-busy
// LDS pipe). Per-accumulator MFMA chain unchanged (o[m][dt] sums kk0->kk1)
// -> bitwise-identical output.
// launch_bounds is plain (256): R5/R6 showed an explicit min-occupancy bound
// makes the allocator split 64 arch-VGPR / 64 AGPR and spill the operand
// arrays (WRITE_SIZE 16MB -> 254/124MB scratch). Unbounded, R2 compiled to
// 72 VGPR; +16 stays well under the 128-reg 4-waves/SIMD cliff.
// NO kb hoist (the +32 regs is what tipped R5/R6 into spilling).
//
// LDS layout (T2): compact 32-elem (64B) rows, 16B-slot XOR swizzle inside
// each 128B row-pair: slot(row,chunk) = ((row&1)*4+chunk) ^ ((row>>1)&7).
// Logical P layout unchanged (sigma contract with vpT). LDS 32KB.
// ---------------------------------------------------------------------------
__device__ __forceinline__ int swz(int row, int chunk) {
    // element offset into a [rows][32] bf16 tile, 16B-slot swizzled
    return (row >> 1) * 64 + (((((row & 1) << 2) | chunk) ^ ((row >> 1) & 7)) << 3);
}

__global__ __launch_bounds__(256) void attn_kernel(
    const __bf16* __restrict__ qp,
    const __bf16* __restrict__ kp,
    const __bf16* __restrict__ vpT,
    __bf16* __restrict__ out)
{
    const int BE = 2048, CK = 1024;
    const int QP = 128 * 32;          // QPs plane stride (elems)
    const int KP = 64 * 32;           // Ks/VTs plane stride

    const int bh = blockIdx.x;       // 0..31 (fast -> K/V L2 locality per XCD)
    const int qt = blockIdx.y;       // 0..31
    const int b = bh >> 3, h = bh & 7;

    __shared__ __attribute__((aligned(16))) __bf16 QPs[2 * 128 * 32]; // Q then P
    __shared__ __attribute__((aligned(16))) __bf16 Ks[2 * 64 * 32];
    __shared__ __attribute__((aligned(16))) __bf16 VTs[2 * 64 * 32];

    const int tid = threadIdx.x;
    const int lane = tid & 63, wv = tid >> 6;
    const int quad = lane >> 4, l15 = lane & 15;

    const size_t ebase = (size_t)b * 512 + h * 64;

    const int srow = tid >> 3;        // 0..31
    const int a8 = (tid & 7) * 8;     // 0..56 (global d-offset)
    const int hp = (tid & 7) >> 2;    // d-half plane select
    const int ch = (tid & 7) & 3;     // 16B chunk within plane

    // stage Q (128 rows x 64 d), hoist this wave's A-frags, then reuse as P
    for (int p = 0; p < 4; p++) {
        bf16x8 v = *(const bf16x8*)&qp[(size_t)(qt * 128 + srow + 32 * p) * BE + ebase + a8];
        *(bf16x8*)&QPs[hp * QP + swz(srow + 32 * p, ch)] = v;
    }
    __syncthreads();
    bf16x8 aq[2][2];
    for (int m = 0; m < 2; m++)
        for (int kk = 0; kk < 2; kk++)
            aq[m][kk] = *(bf16x8*)&QPs[kk * QP + swz(wv * 32 + m * 16 + l15, quad)];

    // preload first K/V chunk into registers
    bf16x8 pk[2], pv[2];
    for (int p = 0; p < 2; p++) {
        pk[p] = *(const bf16x8*)&kp[(size_t)(srow + 32 * p) * BE + ebase + a8];
        pv[p] = *(const bf16x8*)&vpT[((size_t)bh * 64 + srow + 32 * p) * 1024 + a8];
    }

    f32x4 o[2][4];
    for (int m = 0; m < 2; m++)
        for (int dt = 0; dt < 4; dt++) o[m][dt] = (f32x4){0.f, 0.f, 0.f, 0.f};
    float lrowv[2][4] = {{0.f,0.f,0.f,0.f},{0.f,0.f,0.f,0.f}};

    for (int c0 = 0; c0 < CK; c0 += 64) {
        for (int p = 0; p < 2; p++) {
            *(bf16x8*)&Ks[hp * KP + swz(srow + 32 * p, ch)]  = pk[p];
            *(bf16x8*)&VTs[hp * KP + swz(srow + 32 * p, ch)] = pv[p];
        }
        __syncthreads();
        if (c0 + 64 < CK) {
            const int cn = c0 + 64;
            for (int p = 0; p < 2; p++) {
                pk[p] = *(const bf16x8*)&kp[(size_t)(cn + srow + 32 * p) * BE + ebase + a8];
                pv[p] = *(const bf16x8*)&vpT[((size_t)bh * 64 + srow + 32 * p) * 1024 + cn + a8];
            }
        }

        // S = Q K^T, exp2, packed P-stash (wave-private rows of QPs)
        for (int m = 0; m < 2; m++) {
            f32x4 s[4];
            __builtin_amdgcn_s_setprio(1);
            for (int ct = 0; ct < 4; ct++) {
                bf16x8 bk0 = *(bf16x8*)&Ks[swz(ct * 16 + l15, quad)];
                bf16x8 bk1 = *(bf16x8*)&Ks[KP + swz(ct * 16 + l15, quad)];
                f32x4 z = (f32x4){0.f, 0.f, 0.f, 0.f};
                z = MFMA16(aq[m][0], bk0, z);
                z = MFMA16(aq[m][1], bk1, z);
                s[ct] = z;
            }
            __builtin_amdgcn_s_setprio(0);
            for (int r = 0; r < 4; r++) {
                bf16x4 pq;
                for (int ct = 0; ct < 4; ct++) {
                    float pp = __builtin_amdgcn_exp2f(s[ct][r]);
                    lrowv[m][r] += pp;
                    pq[ct] = (__bf16)pp;
                }
                // key ct*16+l15 -> sigma position 4*l15+ct:
                // plane l15>>3, chunk (l15&7)>>1, 8B-half l15&1
                *(bf16x4*)&QPs[(l15 >> 3) * QP
                               + swz(wv * 32 + m * 16 + quad * 4 + r, (l15 & 7) >> 1)
                               + (l15 & 1) * 4] = pq;
            }
        }

        // O += P @ V, kk-outer with per-kk vb hoist (+16 VGPR, PV phase only):
        // 12 b128 reads/iter instead of 20. o[m][dt] still accumulates
        // kk0 -> kk1 (same per-accumulator chain as R2).
        __builtin_amdgcn_s_setprio(1);
        for (int kk = 0; kk < 2; kk++) {
            bf16x8 vb[4];
            for (int dt = 0; dt < 4; dt++)
                vb[dt] = *(bf16x8*)&VTs[kk * KP + swz(dt * 16 + l15, quad)];
            for (int m = 0; m < 2; m++) {
                bf16x8 ap = *(bf16x8*)&QPs[kk * QP + swz(wv * 32 + m * 16 + l15, quad)];
                for (int dt = 0; dt < 4; dt++)
                    o[m][dt] = MFMA16(ap, vb[dt], o[m][dt]);
            }
        }
        __builtin_amdgcn_s_setprio(0);
        __syncthreads();
    }

    for (int m = 0; m < 2; m++)
        for (int r = 0; r < 4; r++) {
            float l = lrowv[m][r];
            l += __shfl_xor(l, 1);
            l += __shfl_xor(l, 2);
            l += __shfl_xor(l, 4);
            l += __shfl_xor(l, 8);
            const float inv = 1.0f / l;
            const int t = qt * 128 + wv * 32 + m * 16 + quad * 4 + r;
            for (int dt = 0; dt < 4; dt++)
                out[(size_t)t * BE + ebase + dt * 16 + l15] = (__bf16)(o[m][dt][r] * inv);
        }
}

// ---------------------------------------------------------------------------
// Scratch plan. d_out = 32 MiB (fp32 out), ws >= 24 MiB.
//   ws:    [0,16) qT -> dead after s2 -> ao;  [16,20) kin, [20,24) vin
//   d_out: [0,16) qp; [16,24) Wckbf -> kpb/vp; [24,32) Wcvbf -> vpT
// ---------------------------------------------------------------------------
extern "C" void kernel_launch(void* const* d_in, const int* in_sizes, int n_in,
                              void* d_out, int out_size, void* d_ws, size_t ws_size,
                              hipStream_t stream)
{
    const float* query = (const float*)d_in[0];
    const void* Wq = d_in[1];  const void* bq = d_in[2];
    const void* Wk = d_in[3];  const void* bk = d_in[4];
    const void* Wv = d_in[5];  const void* bv = d_in[6];
    const float* Wck = (const float*)d_in[7];
    const float* Wcv = (const float*)d_in[8];
    const void* Wo = d_in[9];  const void* bo = d_in[10];

    const size_t MiB = 1u << 20;

    __bf16* qT    = (__bf16*)d_ws;
    __bf16* kin   = (__bf16*)((char*)d_ws + 16 * MiB);
    __bf16* vin   = (__bf16*)((char*)d_ws + 20 * MiB);
    __bf16* ao    = (__bf16*)d_ws;                       // overlays qT (dead)

    __bf16* qp    = (__bf16*)d_out;
    __bf16* Wckbf = (__bf16*)((char*)d_out + 16 * MiB);
    __bf16* Wcvbf = (__bf16*)((char*)d_out + 24 * MiB);
    __bf16* kpb   = (__bf16*)((char*)d_out + 16 * MiB);  // overlays Wckbf (dead)
    __bf16* vp    = (__bf16*)((char*)d_out + 20 * MiB);
    __bf16* vpT   = (__bf16*)((char*)d_out + 24 * MiB);  // overlays Wcvbf (dead)

    // 0a) Wck/Wcv fp32 -> bf16
    cvt<<<dim3(4096, 2), 256, 0, stream>>>(Wck, Wcv, Wckbf, Wcvbf);
    // 0b) qT = transpose(query) bf16 [2048][4096]
    tq<<<dim3(64, 32), 256, 0, stream>>>(query, qT);

    // 1) qp = (query @ Wq^T + bq) * 0.125 * log2(e)   [16384,512] bf16
    gemm_nt<128, 128, 1, 1, 0, 1><<<dim3(4, 128, 1), 256, 0, stream>>>(
        query, query, Wq, Wq, bq, bq, qp, qp, 16384, 512, 512,
        0.125f * 1.44269504088896f);

    // 2) kin = Wckbf @ qT^T, vin = Wcvbf @ qT^T   [1024,2048] bf16
    gemm_nt<64, 128, 0, 0, 0, 0><<<dim3(16, 16, 2), 256, 0, stream>>>(
        Wckbf, Wcvbf, qT, qT, nullptr, nullptr, kin, vin, 1024, 2048, 4096, 1.0f);

    // 3) kpb = kin @ Wk^T + bk, vp = vin @ Wv^T + bv   [4096,512] bf16
    gemm_nt<64, 128, 0, 1, 0, 1><<<dim3(4, 64, 2), 256, 0, stream>>>(
        kin, vin, Wk, Wv, bk, bv, kpb, vp, 4096, 512, 512, 1.0f);

    // 3b) vpT = sigma-permuted head-transpose(vp)
    tv<<<dim3(16, 32), 256, 0, stream>>>(vp, vpT);

    // 4) attention -> ao bf16 (overlays qT)
    attn_kernel<<<dim3(32, 32), 256, 0, stream>>>(qp, kpb, vpT, ao);

    // 5) out = ao @ Wo^T + bo   fp32, rewrites all of d_out
    gemm_nt<128, 128, 0, 1, 1, 1><<<dim3(4, 128, 1), 256, 0, stream>>>(
        ao, ao, Wo, Wo, bo, bo, d_out, d_out, 16384, 512, 512, 1.0f);
}

// Round 8
// 287.128 us; speedup vs baseline: 1.1449x; 1.0129x over previous
//
#include <hip/hip_runtime.h>

typedef float f32x4 __attribute__((ext_vector_type(4)));
typedef __bf16 bf16x8 __attribute__((ext_vector_type(8)));
typedef __bf16 bf16x4 __attribute__((ext_vector_type(4)));

#define MFMA16(a, b, c) __builtin_amdgcn_mfma_f32_16x16x32_bf16((a), (b), (c), 0, 0, 0)

// Async global->LDS, 16B per lane. Dest is wave-uniform base + lane*16 (linear).
__device__ __forceinline__ void gl16(const void* g, void* l) {
    __builtin_amdgcn_global_load_lds(
        (const __attribute__((address_space(1))) void*)g,
        (__attribute__((address_space(3))) void*)l, 16, 0, 0);
}

// Raw prefetch container (fp32 operands only): keep fp32 loads unconverted so
// the cvt (and its waitcnt) lands at LDS-write time, a full iteration later.
template<int F> struct Raw;
template<> struct Raw<0> { bf16x8 v; };
template<> struct Raw<1> { f32x4 a, b; };

template<int F>
__device__ __forceinline__ Raw<F> ldraw(const void* p, size_t idx) {
    Raw<F> r;
    if constexpr (F) {
        const float* q = (const float*)p + idx;
        r.a = *(const f32x4*)q;
        r.b = *(const f32x4*)(q + 4);
    } else {
        r.v = *(const bf16x8*)((const __bf16*)p + idx);
    }
    return r;
}
template<int F>
__device__ __forceinline__ bf16x8 toBf(const Raw<F>& r) {
    if constexpr (F) {
        bf16x8 o;
        o[0] = (__bf16)r.a[0]; o[1] = (__bf16)r.a[1]; o[2] = (__bf16)r.a[2]; o[3] = (__bf16)r.a[3];
        o[4] = (__bf16)r.b[0]; o[5] = (__bf16)r.b[1]; o[6] = (__bf16)r.b[2]; o[7] = (__bf16)r.b[3];
        return o;
    } else {
        return r.v;
    }
}

// ---------------------------------------------------------------------------
// cvt: fp32 -> bf16 bulk convert (Wck / Wcv).
// ---------------------------------------------------------------------------
__global__ __launch_bounds__(256) void cvt(
    const float* __restrict__ a0, const float* __restrict__ a1,
    __bf16* __restrict__ o0, __bf16* __restrict__ o1)
{
    const float* a = blockIdx.y ? a1 : a0;
    __bf16* o = blockIdx.y ? o1 : o0;
    size_t i = ((size_t)blockIdx.x * 256 + threadIdx.x) * 4;
    f32x4 v = *(const f32x4*)&a[i];
    bf16x4 r; r[0]=(__bf16)v[0]; r[1]=(__bf16)v[1]; r[2]=(__bf16)v[2]; r[3]=(__bf16)v[3];
    *(bf16x4*)&o[i] = r;
}

// ---------------------------------------------------------------------------
// tq: query fp32 [4096 t][2048 n] -> qT bf16 [2048 n][4096 t].
// ---------------------------------------------------------------------------
__global__ __launch_bounds__(256) void tq(
    const float* __restrict__ q, __bf16* __restrict__ qT)
{
    __shared__ float Ts[64][65];
    const int t0 = blockIdx.x * 64, n0 = blockIdx.y * 64;
    const int tid = threadIdx.x;
    const int r = tid >> 4, c4 = (tid & 15) * 4;
    for (int p = 0; p < 4; p++) {
        f32x4 v = *(const f32x4*)&q[(size_t)(t0 + r + 16 * p) * 2048 + n0 + c4];
        Ts[r + 16 * p][c4 + 0] = v[0];
        Ts[r + 16 * p][c4 + 1] = v[1];
        Ts[r + 16 * p][c4 + 2] = v[2];
        Ts[r + 16 * p][c4 + 3] = v[3];
    }
    __syncthreads();
    for (int p = 0; p < 4; p++) {
        const int nrow = r + 16 * p;
        bf16x4 o;
        o[0] = (__bf16)Ts[c4 + 0][nrow];
        o[1] = (__bf16)Ts[c4 + 1][nrow];
        o[2] = (__bf16)Ts[c4 + 2][nrow];
        o[3] = (__bf16)Ts[c4 + 3][nrow];
        *(bf16x4*)&qT[(size_t)(n0 + nrow) * 4096 + t0 + c4] = o;
    }
}

// ---------------------------------------------------------------------------
// tv: vp bf16 [4096 (4c+b)][512 (64h+d)] -> vpT bf16 [32 bh][64 d][1024 c'],
// with c' sigma-permuted inside each 64-block: sigma(cc)=4*(cc&15)+(cc>>4).
// ---------------------------------------------------------------------------
__global__ __launch_bounds__(256) void tv(
    const __bf16* __restrict__ vp, __bf16* __restrict__ vpT)
{
    __shared__ __bf16 Ts[64][72];   // [cc][d]
    const int c0 = blockIdx.x * 64;
    const int bh = blockIdx.y, b = bh >> 3, h = bh & 7;
    const int tid = threadIdx.x;
    const int cr = tid >> 3, a8 = (tid & 7) * 8;
    for (int p = 0; p < 2; p++) {
        bf16x8 v = *(const bf16x8*)&vp[(size_t)(4 * (c0 + cr + 32 * p) + b) * 512 + h * 64 + a8];
        *(bf16x8*)&Ts[cr + 32 * p][a8] = v;
    }
    __syncthreads();
    for (int p = 0; p < 2; p++) {
        const int d = cr + 32 * p;
        bf16x8 o;
        for (int u = 0; u < 8; u++) {
            const int pos = a8 + u;                       // permuted position
            const int cc = (pos & 3) * 16 + (pos >> 2);   // source key index
            o[u] = Ts[cc][d];
        }
        *(bf16x8*)&vpT[((size_t)bh * 64 + d) * 1024 + c0 + a8] = o;
    }
}

// ---------------------------------------------------------------------------
// NT GEMM: C = (A @ W^T + bias) * scale.  A:[M,K], W:[N,K] rm.
// BK=64, double-buffered LDS, ONE barrier per K-step. BN=128 config is the
// measured optimum (R4's BN=64 doubled A-panel re-fetch -> +25us).
// Swizzle: slot (r, chunk j) holds logical chunk j ^ (r&7); both-sides
// (pre-swizzled gload source / swizzled ds_write + swizzled read).
// ---------------------------------------------------------------------------
template<int BM, int BN, int AF, int WF, int CF, int BIAS>
__global__ __launch_bounds__(256) void gemm_nt(
    const void* __restrict__ A0, const void* __restrict__ A1,
    const void* __restrict__ W0, const void* __restrict__ W1,
    const void* __restrict__ b0, const void* __restrict__ b1,
    void* __restrict__ C0, void* __restrict__ C1,
    int M, int N, int K, float scale)
{
    const void* A = blockIdx.z ? A1 : A0;
    const void* W = blockIdx.z ? W1 : W0;
    const void* bias = blockIdx.z ? b1 : b0;
    void* C = blockIdx.z ? C1 : C0;

    __shared__ __attribute__((aligned(16))) __bf16 As[2][BM][64];
    __shared__ __attribute__((aligned(16))) __bf16 Ws[2][BN][64];

    const int n0 = blockIdx.x * BN;
    const int m0 = blockIdx.y * BM;
    const int tid = threadIdx.x;
    const int lane = tid & 63, wv = tid >> 6;
    const int quad = lane >> 4, l15 = lane & 15;
    constexpr int WR = BM / 2, MI = WR / 16;
    constexpr int WC = BN / 2, NJ = WC / 16;
    const int wrow = (wv >> 1) * WR, wcol = (wv & 1) * WC;

    // gload_lds geometry: one instr = 8 rows x 128B, dest linear from a
    // wave-uniform base. Lane l lands at (row base+l>>3, chunk l&7); to build
    // the swizzled layout it loads global chunk (l&7) ^ (l>>3).
    const int lrow = lane >> 3;
    const int csrc = ((lane & 7) ^ lrow) * 8;   // source chunk, in elements

    // fp32 reg-staging geometry: thread handles (row tid>>3 + 32p, chunk tid&7),
    // written to the swizzled slot so reads are layout-identical to gload path.
    const int srow = tid >> 3;
    const int sj = tid & 7;
    const int swc = (sj ^ (srow & 7)) * 8;      // swizzled dest column

    constexpr int AP = BM / 32;
    constexpr int WP = BN / 32;
    Raw<AF> pa[AP];
    Raw<WF> pw[WP];

    auto stageA = [&](int buf, int kt) {
        if constexpr (AF == 0) {
            for (int p = 0; p < AP; p++)
                gl16((const __bf16*)A + (size_t)(m0 + wv * 8 + p * 32 + lrow) * K + kt + csrc,
                     &As[buf][wv * 8 + p * 32][0]);
        } else {
            (void)kt;
            for (int p = 0; p < AP; p++)
                *(bf16x8*)&As[buf][srow + 32 * p][swc] = toBf<AF>(pa[p]);
        }
    };
    auto stageW = [&](int buf, int kt) {
        if constexpr (WF == 0) {
            for (int p = 0; p < WP; p++)
                gl16((const __bf16*)W + (size_t)(n0 + wv * 8 + p * 32 + lrow) * K + kt + csrc,
                     &Ws[buf][wv * 8 + p * 32][0]);
        } else {
            (void)kt;
            for (int p = 0; p < WP; p++)
                *(bf16x8*)&Ws[buf][srow + 32 * p][swc] = toBf<WF>(pw[p]);
        }
    };
    auto loadA = [&](int kt) {
        if constexpr (AF == 1)
            for (int p = 0; p < AP; p++)
                pa[p] = ldraw<AF>(A, (size_t)(m0 + srow + 32 * p) * K + kt + sj * 8);
    };
    auto loadW = [&](int kt) {
        if constexpr (WF == 1)
            for (int p = 0; p < WP; p++)
                pw[p] = ldraw<WF>(W, (size_t)(n0 + srow + 32 * p) * K + kt + sj * 8);
    };

    f32x4 acc[MI][NJ];
    for (int i = 0; i < MI; i++)
        for (int j = 0; j < NJ; j++)
            acc[i][j] = (f32x4){0.f, 0.f, 0.f, 0.f};

    // prologue: tile 0 -> buf 0; fp32 operands additionally prefetch tile 1
    loadA(0);
    loadW(0);
    stageA(0, 0);
    stageW(0, 0);
    loadA(64);
    loadW(64);
    __syncthreads();

    const int NT = K >> 6;
    for (int t = 0; t < NT; ++t) {
        const int cur = t & 1;
        if (t + 1 < NT) {
            stageA(cur ^ 1, (t + 1) * 64);   // fp32 path: writes pregs (tile t+1)
            stageW(cur ^ 1, (t + 1) * 64);
            if (t + 2 < NT) { loadA((t + 2) * 64); loadW((t + 2) * 64); }
        }
        bf16x8 a0[MI], a1[MI], bv0[NJ], bv1[NJ];
        for (int i = 0; i < MI; i++) {
            const int r = wrow + i * 16 + l15;
            a0[i] = *(const bf16x8*)&As[cur][r][(quad ^ (r & 7)) * 8];
            a1[i] = *(const bf16x8*)&As[cur][r][((4 + quad) ^ (r & 7)) * 8];
        }
        for (int j = 0; j < NJ; j++) {
            const int r = wcol + j * 16 + l15;
            bv0[j] = *(const bf16x8*)&Ws[cur][r][(quad ^ (r & 7)) * 8];
            bv1[j] = *(const bf16x8*)&Ws[cur][r][((4 + quad) ^ (r & 7)) * 8];
        }
        for (int i = 0; i < MI; i++)
            for (int j = 0; j < NJ; j++) {
                acc[i][j] = MFMA16(a0[i], bv0[j], acc[i][j]);
                acc[i][j] = MFMA16(a1[i], bv1[j], acc[i][j]);
            }
        __syncthreads();
    }

    for (int i = 0; i < MI; i++) {
        const int rbase = m0 + wrow + i * 16 + quad * 4;
        for (int j = 0; j < NJ; j++) {
            const int col = n0 + wcol + j * 16 + l15;
            float bvv = 0.f;
            if constexpr (BIAS) bvv = ((const float*)bias)[col];
            for (int r = 0; r < 4; r++) {
                float v = (acc[i][j][r] + bvv) * scale;
                size_t off = (size_t)(rbase + r) * N + col;
                if constexpr (CF) ((float*)C)[off] = v;
                else              ((__bf16*)C)[off] = (__bf16)v;
            }
        }
    }
}

// ---------------------------------------------------------------------------
// Flash attention, exp2-domain (qp pre-scaled by 0.125*log2e), no online
// rescale (scores bounded ~6 sigma ~ 1.6 << fp32 exp2 overflow at 128).
// 128 q-rows per block x one (b,h); 4 waves x 32 q-rows; K/V chunk = 64.
//
// Round-8: QK restructured ct-outer / m-inner with s[2][4] accumulators so
// each K-fragment is read ONCE per iter (16 -> 8 b128). R7 showed the
// compiler had already CSE'd the PV vb reads (VGPR stayed 72), so the real
// R2/R7 op count was 32 b128 + 8 b64 /wave-iter; LDS pipe ~79% busy
// (432 cyc/iter/wave x 16 waves/CU vs 8.75k cyc/iter-CU measured). The
// bk reads could NOT be CSE'd across the m-loop because P-stash ds_writes
// sat between the two m passes (aliasing). ct-outer removes that: all 16
// QK MFMAs first, stash after. Per-accumulator chain unchanged
// (z=0 -> +aq[m][0]*bk0 -> +aq[m][1]*bk1) -> bitwise-identical.
// Cost: +16 VGPR (s 16->32 f32), peak ~88-96, NO launch_bounds minimum
// (R5/R6: an explicit min-occupancy bound made the allocator split
// 64 arch/64 acc and spill -> WRITE_SIZE 124-254MB scratch).
// Go/no-go: WRITE_SIZE 16384 KB, VGPR <= 128.
// LDS ops now 24 b128 + 8 b64 = 336 cyc/iter/wave (-22% on the hot pipe).
//
// LDS layout (T2): compact 32-elem (64B) rows, 16B-slot XOR swizzle inside
// each 128B row-pair: slot(row,chunk) = ((row&1)*4+chunk) ^ ((row>>1)&7).
// Logical P layout unchanged (sigma contract with vpT). LDS 32KB.
// ---------------------------------------------------------------------------
__device__ __forceinline__ int swz(int row, int chunk) {
    // element offset into a [rows][32] bf16 tile, 16B-slot swizzled
    return (row >> 1) * 64 + (((((row & 1) << 2) | chunk) ^ ((row >> 1) & 7)) << 3);
}

__global__ __launch_bounds__(256) void attn_kernel(
    const __bf16* __restrict__ qp,
    const __bf16* __restrict__ kp,
    const __bf16* __restrict__ vpT,
    __bf16* __restrict__ out)
{
    const int BE = 2048, CK = 1024;
    const int QP = 128 * 32;          // QPs plane stride (elems)
    const int KP = 64 * 32;           // Ks/VTs plane stride

    const int bh = blockIdx.x;       // 0..31 (fast -> K/V L2 locality per XCD)
    const int qt = blockIdx.y;       // 0..31
    const int b = bh >> 3, h = bh & 7;

    __shared__ __attribute__((aligned(16))) __bf16 QPs[2 * 128 * 32]; // Q then P
    __shared__ __attribute__((aligned(16))) __bf16 Ks[2 * 64 * 32];
    __shared__ __attribute__((aligned(16))) __bf16 VTs[2 * 64 * 32];

    const int tid = threadIdx.x;
    const int lane = tid & 63, wv = tid >> 6;
    const int quad = lane >> 4, l15 = lane & 15;

    const size_t ebase = (size_t)b * 512 + h * 64;

    const int srow = tid >> 3;        // 0..31
    const int a8 = (tid & 7) * 8;     // 0..56 (global d-offset)
    const int hp = (tid & 7) >> 2;    // d-half plane select
    const int ch = (tid & 7) & 3;     // 16B chunk within plane

    // stage Q (128 rows x 64 d), hoist this wave's A-frags, then reuse as P
    for (int p = 0; p < 4; p++) {
        bf16x8 v = *(const bf16x8*)&qp[(size_t)(qt * 128 + srow + 32 * p) * BE + ebase + a8];
        *(bf16x8*)&QPs[hp * QP + swz(srow + 32 * p, ch)] = v;
    }
    __syncthreads();
    bf16x8 aq[2][2];
    for (int m = 0; m < 2; m++)
        for (int kk = 0; kk < 2; kk++)
            aq[m][kk] = *(bf16x8*)&QPs[kk * QP + swz(wv * 32 + m * 16 + l15, quad)];

    // preload first K/V chunk into registers
    bf16x8 pk[2], pv[2];
    for (int p = 0; p < 2; p++) {
        pk[p] = *(const bf16x8*)&kp[(size_t)(srow + 32 * p) * BE + ebase + a8];
        pv[p] = *(const bf16x8*)&vpT[((size_t)bh * 64 + srow + 32 * p) * 1024 + a8];
    }

    f32x4 o[2][4];
    for (int m = 0; m < 2; m++)
        for (int dt = 0; dt < 4; dt++) o[m][dt] = (f32x4){0.f, 0.f, 0.f, 0.f};
    float lrowv[2][4] = {{0.f,0.f,0.f,0.f},{0.f,0.f,0.f,0.f}};

    for (int c0 = 0; c0 < CK; c0 += 64) {
        for (int p = 0; p < 2; p++) {
            *(bf16x8*)&Ks[hp * KP + swz(srow + 32 * p, ch)]  = pk[p];
            *(bf16x8*)&VTs[hp * KP + swz(srow + 32 * p, ch)] = pv[p];
        }
        __syncthreads();
        if (c0 + 64 < CK) {
            const int cn = c0 + 64;
            for (int p = 0; p < 2; p++) {
                pk[p] = *(const bf16x8*)&kp[(size_t)(cn + srow + 32 * p) * BE + ebase + a8];
                pv[p] = *(const bf16x8*)&vpT[((size_t)bh * 64 + srow + 32 * p) * 1024 + cn + a8];
            }
        }

        // S = Q K^T, ct-outer: each K-fragment read once (8 b128/iter).
        // All 16 MFMAs issue before the stash phase; chain per s[m][ct]
        // identical to R2/R7 (zero-init, aq0*bk0 then aq1*bk1).
        f32x4 s[2][4];
        __builtin_amdgcn_s_setprio(1);
        for (int ct = 0; ct < 4; ct++) {
            bf16x8 bk0 = *(bf16x8*)&Ks[swz(ct * 16 + l15, quad)];
            bf16x8 bk1 = *(bf16x8*)&Ks[KP + swz(ct * 16 + l15, quad)];
            for (int m = 0; m < 2; m++) {
                f32x4 z = (f32x4){0.f, 0.f, 0.f, 0.f};
                z = MFMA16(aq[m][0], bk0, z);
                z = MFMA16(aq[m][1], bk1, z);
                s[m][ct] = z;
            }
        }
        __builtin_amdgcn_s_setprio(0);

        // exp2 + packed P-stash (wave-private rows of QPs)
        for (int m = 0; m < 2; m++) {
            for (int r = 0; r < 4; r++) {
                bf16x4 pq;
                for (int ct = 0; ct < 4; ct++) {
                    float pp = __builtin_amdgcn_exp2f(s[m][ct][r]);
                    lrowv[m][r] += pp;
                    pq[ct] = (__bf16)pp;
                }
                // key ct*16+l15 -> sigma position 4*l15+ct:
                // plane l15>>3, chunk (l15&7)>>1, 8B-half l15&1
                *(bf16x4*)&QPs[(l15 >> 3) * QP
                               + swz(wv * 32 + m * 16 + quad * 4 + r, (l15 & 7) >> 1)
                               + (l15 & 1) * 4] = pq;
            }
        }

        // O += P @ V, kk-outer with per-kk vb hoist.
        // o[m][dt] accumulates kk0 -> kk1 (same chain as R2/R7).
        __builtin_amdgcn_s_setprio(1);
        for (int kk = 0; kk < 2; kk++) {
            bf16x8 vb[4];
            for (int dt = 0; dt < 4; dt++)
                vb[dt] = *(bf16x8*)&VTs[kk * KP + swz(dt * 16 + l15, quad)];
            for (int m = 0; m < 2; m++) {
                bf16x8 ap = *(bf16x8*)&QPs[kk * QP + swz(wv * 32 + m * 16 + l15, quad)];
                for (int dt = 0; dt < 4; dt++)
                    o[m][dt] = MFMA16(ap, vb[dt], o[m][dt]);
            }
        }
        __builtin_amdgcn_s_setprio(0);
        __syncthreads();
    }

    for (int m = 0; m < 2; m++)
        for (int r = 0; r < 4; r++) {
            float l = lrowv[m][r];
            l += __shfl_xor(l, 1);
            l += __shfl_xor(l, 2);
            l += __shfl_xor(l, 4);
            l += __shfl_xor(l, 8);
            const float inv = 1.0f / l;
            const int t = qt * 128 + wv * 32 + m * 16 + quad * 4 + r;
            for (int dt = 0; dt < 4; dt++)
                out[(size_t)t * BE + ebase + dt * 16 + l15] = (__bf16)(o[m][dt][r] * inv);
        }
}

// ---------------------------------------------------------------------------
// Scratch plan. d_out = 32 MiB (fp32 out), ws >= 24 MiB.
//   ws:    [0,16) qT -> dead after s2 -> ao;  [16,20) kin, [20,24) vin
//   d_out: [0,16) qp; [16,24) Wckbf -> kpb/vp; [24,32) Wcvbf -> vpT
// ---------------------------------------------------------------------------
extern "C" void kernel_launch(void* const* d_in, const int* in_sizes, int n_in,
                              void* d_out, int out_size, void* d_ws, size_t ws_size,
                              hipStream_t stream)
{
    const float* query = (const float*)d_in[0];
    const void* Wq = d_in[1];  const void* bq = d_in[2];
    const void* Wk = d_in[3];  const void* bk = d_in[4];
    const void* Wv = d_in[5];  const void* bv = d_in[6];
    const float* Wck = (const float*)d_in[7];
    const float* Wcv = (const float*)d_in[8];
    const void* Wo = d_in[9];  const void* bo = d_in[10];

    const size_t MiB = 1u << 20;

    __bf16* qT    = (__bf16*)d_ws;
    __bf16* kin   = (__bf16*)((char*)d_ws + 16 * MiB);
    __bf16* vin   = (__bf16*)((char*)d_ws + 20 * MiB);
    __bf16* ao    = (__bf16*)d_ws;                       // overlays qT (dead)

    __bf16* qp    = (__bf16*)d_out;
    __bf16* Wckbf = (__bf16*)((char*)d_out + 16 * MiB);
    __bf16* Wcvbf = (__bf16*)((char*)d_out + 24 * MiB);
    __bf16* kpb   = (__bf16*)((char*)d_out + 16 * MiB);  // overlays Wckbf (dead)
    __bf16* vp    = (__bf16*)((char*)d_out + 20 * MiB);
    __bf16* vpT   = (__bf16*)((char*)d_out + 24 * MiB);  // overlays Wcvbf (dead)

    // 0a) Wck/Wcv fp32 -> bf16
    cvt<<<dim3(4096, 2), 256, 0, stream>>>(Wck, Wcv, Wckbf, Wcvbf);
    // 0b) qT = transpose(query) bf16 [2048][4096]
    tq<<<dim3(64, 32), 256, 0, stream>>>(query, qT);

    // 1) qp = (query @ Wq^T + bq) * 0.125 * log2(e)   [16384,512] bf16
    gemm_nt<128, 128, 1, 1, 0, 1><<<dim3(4, 128, 1), 256, 0, stream>>>(
        query, query, Wq, Wq, bq, bq, qp, qp, 16384, 512, 512,
        0.125f * 1.44269504088896f);

    // 2) kin = Wckbf @ qT^T, vin = Wcvbf @ qT^T   [1024,2048] bf16
    gemm_nt<64, 128, 0, 0, 0, 0><<<dim3(16, 16, 2), 256, 0, stream>>>(
        Wckbf, Wcvbf, qT, qT, nullptr, nullptr, kin, vin, 1024, 2048, 4096, 1.0f);

    // 3) kpb = kin @ Wk^T + bk, vp = vin @ Wv^T + bv   [4096,512] bf16
    gemm_nt<64, 128, 0, 1, 0, 1><<<dim3(4, 64, 2), 256, 0, stream>>>(
        kin, vin, Wk, Wv, bk, bv, kpb, vp, 4096, 512, 512, 1.0f);

    // 3b) vpT = sigma-permuted head-transpose(vp)
    tv<<<dim3(16, 32), 256, 0, stream>>>(vp, vpT);

    // 4) attention -> ao bf16 (overlays qT)
    attn_kernel<<<dim3(32, 32), 256, 0, stream>>>(qp, kpb, vpT, ao);

    // 5) out = ao @ Wo^T + bo   fp32, rewrites all of d_out
    gemm_nt<128, 128, 0, 1, 1, 1><<<dim3(4, 128, 1), 256, 0, stream>>>(
        ao, ao, Wo, Wo, bo, bo, d_out, d_out, 16384, 512, 512, 1.0f);
}